// Round 9
// baseline (81.794 us; speedup 1.0000x reference)
//
#include <hip/hip_runtime.h>

// GraphUpSamplingLayer: 3-D k=1 NN argmin + batched feature gather.
// B=4, C=512, M=2048 (coarse points), N=8192 (dense points), D=3.
//
// ROUND 9 = live v8 (v2-structure + 6-op score) + v6x4 probe (dead, ~90us,
// lands #1 in top-5 to expose VGPR_Count/VALUBusy/FETCH for the v6 class).
constexpr int B = 4;
constexpr int C = 512;
constexpr int M = 2048;
constexpr int N = 8192;

// ---------------------------------------------------------------------------
// v8 argmin (LIVE): query-per-lane, candidate-slice-per-wave (v2 structure,
// measured best at 17us with the 9-op form), 6-op half-expanded score.
// Block = 512 thr = 8 waves; 64 queries/block (one per lane, same in every
// wave); wave w scans [256w, 256w+256) via uniform-address ds_read_b128
// broadcast (1 LDS instr per 64 pairs). Per pair: 3 fma + cmp + 2 cndmask.
// Cross-wave merge: packed u64 (monotonic-key(d)<<32 | m) min — key is the
// order-preserving float->u32 map (handles NEGATIVE scores, unlike raw bits).
// Tie-break = jnp first-occurrence: in-lane m-ascending strict <; cross-slice
// equal-d -> smaller m via low word. Grid 512 blocks = 2 blocks/CU.
// ---------------------------------------------------------------------------
__global__ __launch_bounds__(512) void nn_argmin_v8(
    const float* __restrict__ pos,      // [B][N][3]
    const float* __restrict__ sub_pos,  // [B][M][3]
    int* __restrict__ idx_out)          // [B][N]
{
    __shared__ float4 sp[M];                   // 32 KB: (x, y, z, ||s||^2/2)
    __shared__ unsigned long long red[8][64];  // 4 KB

    const int b  = blockIdx.x >> 7;            // 128 blocks per batch
    const int n0 = (blockIdx.x & 127) << 6;    // 64 queries per block
    const int t  = threadIdx.x;
    const int w    = t >> 6;                   // wave 0..7
    const int lane = t & 63;

    const float* spb = sub_pos + (size_t)b * (M * 3);
    for (int i = t; i < M; i += 512) {
        const float x = spb[i * 3 + 0];
        const float y = spb[i * 3 + 1];
        const float z = spb[i * 3 + 2];
        sp[i] = make_float4(x, y, z, 0.5f * fmaf(z, z, fmaf(y, y, x * x)));
    }
    __syncthreads();

    const int n = n0 + lane;
    const float* pp = pos + ((size_t)b * N + n) * 3;
    const float px = pp[0], py = pp[1], pz = pp[2];

    float best = 1e30f;
    int bm = 0;
    const int m0 = w << 8;                     // this wave's 256-candidate slice
    float4 c = sp[m0];                         // 1-deep uniform prefetch
    #pragma unroll 8
    for (int j = 0; j < 256; ++j) {
        const float4 cc = c;
        c = sp[m0 + ((j + 1) & 255)];
        float s = fmaf(-cc.x, px, cc.w);
        s = fmaf(-cc.y, py, s);
        s = fmaf(-cc.z, pz, s);
        const bool lt = s < best;              // strict <: first index in slice
        best = lt ? s : best;
        bm   = lt ? (m0 + j) : bm;
    }

    // Order-preserving float->u32 key (scores can be negative).
    unsigned int fb = __float_as_uint(best);
    fb ^= (unsigned int)((int)fb >> 31) | 0x80000000u;
    red[w][lane] = ((unsigned long long)fb << 32) | (unsigned int)bm;
    __syncthreads();

    if (w == 0) {
        unsigned long long k = red[0][lane];
        #pragma unroll
        for (int ww = 1; ww < 8; ++ww) {
            const unsigned long long o = red[ww][lane];
            k = (o < k) ? o : k;
        }
        idx_out[(size_t)b * N + n] = (int)(unsigned int)k;
    }
}

// ---------------------------------------------------------------------------
// v6x4 PROBE (DEAD, this round only): exact v6 body, 4 internal reps
// (asm-perturbed queries defeat cross-rep CSE; rep-distinct dead stores).
// One ~90us dispatch -> top-5 row exposes VGPR_Count (64 == capped/spilling),
// FETCH_SIZE (spill traffic), VALUBusy, OccupancyPercent for the v6 class.
// ---------------------------------------------------------------------------
__global__ __launch_bounds__(512, 8) void nn_argmin_v6_probe(
    const float* __restrict__ pos,
    const float* __restrict__ sub_pos,
    int* __restrict__ idx_dead)
{
    __shared__ float4 sp[M];

    const int b  = blockIdx.x >> 8;
    const int n0 = (blockIdx.x & 255) << 5;
    const int t  = threadIdx.x;
    const int w    = t >> 6;
    const int lane = t & 63;

    const float* spb = sub_pos + (size_t)b * (M * 3);
    #pragma unroll
    for (int i = t; i < M; i += 512) {
        const float x = spb[i * 3 + 0];
        const float y = spb[i * 3 + 1];
        const float z = spb[i * 3 + 2];
        sp[i] = make_float4(x, y, z, 0.5f * fmaf(z, z, fmaf(y, y, x * x)));
    }
    __syncthreads();

    const float* pp = pos + ((size_t)b * N + n0 + (w << 2)) * 3;
    float px0 = pp[0],  py0 = pp[1],  pz0 = pp[2];
    float px1 = pp[3],  py1 = pp[4],  pz1 = pp[5];
    float px2 = pp[6],  py2 = pp[7],  pz2 = pp[8];
    float px3 = pp[9],  py3 = pp[10], pz3 = pp[11];

    for (int rep = 0; rep < 4; ++rep) {
        // Defeat cross-rep CSE: queries become opaque each rep.
        asm volatile("" : "+v"(px0), "+v"(py0), "+v"(pz0),
                          "+v"(px1), "+v"(py1), "+v"(pz1),
                          "+v"(px2), "+v"(py2), "+v"(pz2),
                          "+v"(px3), "+v"(py3), "+v"(pz3));
        float b0 = 1e30f, b1 = 1e30f, b2 = 1e30f, b3 = 1e30f;
        int   m0 = 0,     m1 = 0,     m2 = 0,     m3 = 0;

        float4 c = sp[lane];
        #pragma unroll 4
        for (int i = 0; i < 32; ++i) {
            const float4 cc = c;
            c = sp[((((i + 1) & 31) << 6) + lane)];
            const int m = (i << 6) + lane;
            float s;
            s = fmaf(-cc.x, px0, cc.w); s = fmaf(-cc.y, py0, s); s = fmaf(-cc.z, pz0, s);
            { const bool lt = s < b0; b0 = lt ? s : b0; m0 = lt ? m : m0; }
            s = fmaf(-cc.x, px1, cc.w); s = fmaf(-cc.y, py1, s); s = fmaf(-cc.z, pz1, s);
            { const bool lt = s < b1; b1 = lt ? s : b1; m1 = lt ? m : m1; }
            s = fmaf(-cc.x, px2, cc.w); s = fmaf(-cc.y, py2, s); s = fmaf(-cc.z, pz2, s);
            { const bool lt = s < b2; b2 = lt ? s : b2; m2 = lt ? m : m2; }
            s = fmaf(-cc.x, px3, cc.w); s = fmaf(-cc.y, py3, s); s = fmaf(-cc.z, pz3, s);
            { const bool lt = s < b3; b3 = lt ? s : b3; m3 = lt ? m : m3; }
        }

        #pragma unroll
        for (int off = 1; off < 64; off <<= 1) {
            float ob; int om;
            ob = __shfl_xor(b0, off, 64); om = __shfl_xor(m0, off, 64);
            if (ob < b0 || (ob == b0 && om < m0)) { b0 = ob; m0 = om; }
            ob = __shfl_xor(b1, off, 64); om = __shfl_xor(m1, off, 64);
            if (ob < b1 || (ob == b1 && om < m1)) { b1 = ob; m1 = om; }
            ob = __shfl_xor(b2, off, 64); om = __shfl_xor(m2, off, 64);
            if (ob < b2 || (ob == b2 && om < m2)) { b2 = ob; m2 = om; }
            ob = __shfl_xor(b3, off, 64); om = __shfl_xor(m3, off, 64);
            if (ob < b3 || (ob == b3 && om < m3)) { b3 = ob; m3 = om; }
        }

        if (lane == 0) {
            // rep-distinct addresses: all 4 reps' stores are live.
            int* o = idx_dead + (size_t)b * N + n0 + (w << 2) + rep;
            o[0] = m0; o[1] = m1; o[2] = m2; o[3] = m3;
        }
    }
}

// ---------------------------------------------------------------------------
// Phase 2: out[b][c][n] = sub_x[b][c][idx[b][n]]  (~85% of write roofline)
// ---------------------------------------------------------------------------
__global__ __launch_bounds__(256) void gather_kernel(
    const float* __restrict__ sub_x,  // [B][C][M]
    const int* __restrict__ idx,      // [B][N]
    float* __restrict__ out)          // [B][C][N]
{
    __shared__ float row[M];          // 8 KB

    const int b = blockIdx.x >> 9;    // C = 512
    const int c = blockIdx.x & 511;
    const int t = threadIdx.x;

    const float* rsrc = sub_x + ((size_t)b * C + c) * M;
    for (int i = t; i < M; i += 256) row[i] = rsrc[i];
    __syncthreads();

    const int4* iv = (const int4*)(idx + (size_t)b * N);
    float4* ov = (float4*)(out + ((size_t)b * C + c) * N);
    #pragma unroll
    for (int i = t; i < N / 4; i += 256) {
        const int4 ii = iv[i];
        float4 v;
        v.x = row[ii.x];
        v.y = row[ii.y];
        v.z = row[ii.z];
        v.w = row[ii.w];
        ov[i] = v;
    }
}

extern "C" void kernel_launch(void* const* d_in, const int* in_sizes, int n_in,
                              void* d_out, int out_size, void* d_ws, size_t ws_size,
                              hipStream_t stream) {
    const float* sub_x   = (const float*)d_in[0];  // [B][C][M]
    const float* sub_pos = (const float*)d_in[1];  // [B][M][3]
    const float* pos     = (const float*)d_in[2];  // [B][N][3]
    float* out = (float*)d_out;                    // [B][C][N]
    int* idx      = (int*)d_ws;                          // live idx (128 KB)
    int* idx_dead = (int*)((char*)d_ws + (1 << 20));     // probe sink

    nn_argmin_v8<<<B * (N / 64), 512, 0, stream>>>(pos, sub_pos, idx);
    gather_kernel<<<B * C, 256, 0, stream>>>(sub_x, idx, out);
    nn_argmin_v6_probe<<<B * (N / 32), 512, 0, stream>>>(pos, sub_pos, idx_dead);
}

// Round 10
// 32.330 us; speedup vs baseline: 2.5299x; 2.5299x over previous
//
#include <hip/hip_runtime.h>

// GraphUpSamplingLayer: 3-D k=1 NN argmin + batched feature gather.
// B=4, C=512, M=2048 (coarse points), N=8192 (dense points), D=3.
//
// Final structure (R9-measured): argmin v8 ~8.5us (85% of VALU-issue floor),
// gather ~11.7us (7.2 TB/s effective -- above the 6.3 TB/s copy ceiling).
constexpr int B = 4;
constexpr int C = 512;
constexpr int M = 2048;
constexpr int N = 8192;

// ---------------------------------------------------------------------------
// v8 argmin: query-per-lane, candidate-slice-per-wave, uniform-broadcast LDS.
// Block = 512 thr = 8 waves; 64 queries/block (one per lane, same set in
// every wave); wave w scans candidates [256w, 256w+256) via uniform-address
// ds_read_b128 (wave broadcast, 1 LDS instr / 64 pairs), 1-deep prefetch.
// Score = ||s||^2/2 - p.s (h staged in float4.w): 3 fma + cmp + 2 cndmask
// = 6 VALU/pair (validated absmax 0.0 in R7/R8/R9).
// Cross-wave merge: packed u64 (monotonic-key(d)<<32 | m) min, where key is
// the order-preserving float->u32 map (scores can be negative).
// Tie-break = jnp.argmin first-occurrence: in-lane m-ascending strict <;
// equal keys across slices -> smaller m wins via low word.
// Grid 512 blocks = 2 blocks/CU = 4 waves/SIMD; VALU-issue-bound.
// ---------------------------------------------------------------------------
__global__ __launch_bounds__(512) void nn_argmin_v8(
    const float* __restrict__ pos,      // [B][N][3]
    const float* __restrict__ sub_pos,  // [B][M][3]
    int* __restrict__ idx_out)          // [B][N]
{
    __shared__ float4 sp[M];                   // 32 KB: (x, y, z, ||s||^2/2)
    __shared__ unsigned long long red[8][64];  // 4 KB

    const int b  = blockIdx.x >> 7;            // 128 blocks per batch
    const int n0 = (blockIdx.x & 127) << 6;    // 64 queries per block
    const int t  = threadIdx.x;
    const int w    = t >> 6;                   // wave 0..7
    const int lane = t & 63;

    const float* spb = sub_pos + (size_t)b * (M * 3);
    for (int i = t; i < M; i += 512) {
        const float x = spb[i * 3 + 0];
        const float y = spb[i * 3 + 1];
        const float z = spb[i * 3 + 2];
        sp[i] = make_float4(x, y, z, 0.5f * fmaf(z, z, fmaf(y, y, x * x)));
    }
    __syncthreads();

    const int n = n0 + lane;
    const float* pp = pos + ((size_t)b * N + n) * 3;
    const float px = pp[0], py = pp[1], pz = pp[2];

    float best = 1e30f;
    int bm = 0;
    const int m0 = w << 8;                     // this wave's 256-candidate slice
    float4 c = sp[m0];                         // 1-deep uniform prefetch
    #pragma unroll 8
    for (int j = 0; j < 256; ++j) {
        const float4 cc = c;
        c = sp[m0 + ((j + 1) & 255)];
        float s = fmaf(-cc.x, px, cc.w);
        s = fmaf(-cc.y, py, s);
        s = fmaf(-cc.z, pz, s);
        const bool lt = s < best;              // strict <: first index in slice
        best = lt ? s : best;
        bm   = lt ? (m0 + j) : bm;
    }

    // Order-preserving float->u32 key (scores can be negative).
    unsigned int fb = __float_as_uint(best);
    fb ^= (unsigned int)((int)fb >> 31) | 0x80000000u;
    red[w][lane] = ((unsigned long long)fb << 32) | (unsigned int)bm;
    __syncthreads();

    if (w == 0) {
        unsigned long long k = red[0][lane];
        #pragma unroll
        for (int ww = 1; ww < 8; ++ww) {
            const unsigned long long o = red[ww][lane];
            k = (o < k) ? o : k;
        }
        idx_out[(size_t)b * N + n] = (int)(unsigned int)k;
    }
}

// ---------------------------------------------------------------------------
// Phase 2: out[b][c][n] = sub_x[b][c][idx[b][n]]
// One block per (b,c): row staged once in LDS (coalesced), idx streamed as
// int4 (L2-resident), float4-coalesced writes. 84 MB HBM in ~11.7us
// = 7.2 TB/s effective -- at/above the measured copy ceiling.
// ---------------------------------------------------------------------------
__global__ __launch_bounds__(256) void gather_kernel(
    const float* __restrict__ sub_x,  // [B][C][M]
    const int* __restrict__ idx,      // [B][N]
    float* __restrict__ out)          // [B][C][N]
{
    __shared__ float row[M];          // 8 KB

    const int b = blockIdx.x >> 9;    // C = 512
    const int c = blockIdx.x & 511;
    const int t = threadIdx.x;

    const float* rsrc = sub_x + ((size_t)b * C + c) * M;
    for (int i = t; i < M; i += 256) row[i] = rsrc[i];
    __syncthreads();

    const int4* iv = (const int4*)(idx + (size_t)b * N);
    float4* ov = (float4*)(out + ((size_t)b * C + c) * N);
    #pragma unroll
    for (int i = t; i < N / 4; i += 256) {
        const int4 ii = iv[i];
        float4 v;
        v.x = row[ii.x];
        v.y = row[ii.y];
        v.z = row[ii.z];
        v.w = row[ii.w];
        ov[i] = v;
    }
}

extern "C" void kernel_launch(void* const* d_in, const int* in_sizes, int n_in,
                              void* d_out, int out_size, void* d_ws, size_t ws_size,
                              hipStream_t stream) {
    const float* sub_x   = (const float*)d_in[0];  // [B][C][M]
    const float* sub_pos = (const float*)d_in[1];  // [B][M][3]
    const float* pos     = (const float*)d_in[2];  // [B][N][3]
    float* out = (float*)d_out;                    // [B][C][N]
    int* idx = (int*)d_ws;                         // B*N*4 = 128 KB scratch

    nn_argmin_v8<<<B * (N / 64), 512, 0, stream>>>(pos, sub_pos, idx);
    gather_kernel<<<B * C, 256, 0, stream>>>(sub_x, idx, out);
}